// Round 7
// baseline (83.110 us; speedup 1.0000x reference)
//
#include <hip/hip_runtime.h>
#include <math.h>

// Problem geometry (fixed by the reference's setup_inputs)
#define NAUX 32
#define NB   64
#define NF   80
#define NT   640
#define PERB (NF * NT)          // 51200 elements per batch
#define NTOT (NB * PERB)        // 3276800 elements per channel
#define NGRP (NTOT / 4)         // 819200 4-element groups -> mask bytes
#define THR  20.0f
#define ASEG 10                 // A: blocks per batch (5120 elems each)
#define AUNR 5                  // A: k-chunks per wave-run
#define WRUNA (AUNR * 256)      // A: elements per wave run (1280)
#define RUNB  (PERB / 4)        // B: elements per wave run (12800, 1/4 batch)
#define STEPB 512               // B: elements per wave per iter (64 lanes x 8)
#define NITB  (RUNB / STEPB)    // 25 iterations

// clang native vector type -> accepted by __builtin_nontemporal_load
typedef float f32x4 __attribute__((ext_vector_type(4)));

// x >= 20.0f  <=>  x > predecessor(20.0f); lets the whole peak predicate be
// one v_max3_f32 + one compare:  peak(x) <=> x > max3(left, right, THRM)
#define THRM __uint_as_float(0x419FFFFFu)   // 19.999998...f

// ---------------------------------------------------------------------------
// Strict-local-max predicate over the FULL flattened [B,F,T] channel (peaks
// cross batch boundaries; only channel-flat 0 and NTOT-1 excluded).
// clip(min=0) is a no-op given the >=20 requirement.
// Mask layout: byte g holds the 4-bit predicate nibble for elements 4g..4g+3
// (element-order; producer A writes bytes, consumer B reads ushorts).
// ---------------------------------------------------------------------------

// Kernel A: 640 blocks; block covers 5120 elements = 4 wave-runs of 1280.
__global__ __launch_bounds__(256) void strain_mask_kernel(
    const float* __restrict__ qs,
    unsigned char* __restrict__ maskb,
    unsigned int* __restrict__ c1part)
{
    const int tid  = threadIdx.x;
    const int lane = tid & 63;
    const int w    = tid >> 6;
    const int base = blockIdx.x * (4 * WRUNA) + w * WRUNA + lane * 4;

    f32x4 v[AUNR];
    #pragma unroll
    for (int k = 0; k < AUNR; ++k)
        v[k] = __builtin_nontemporal_load(reinterpret_cast<const f32x4*>(qs + base + k * 256));

    float xmE = INFINITY, xpE = INFINITY;
    if (lane == 0)  { const int g = base - 1;                    if (g >= 0)   xmE = qs[g]; }
    if (lane == 63) { const int g = base + (AUNR - 1) * 256 + 4; if (g < NTOT) xpE = qs[g]; }

    unsigned int cnt = 0;
    #pragma unroll
    for (int k = 0; k < AUNR; ++k) {
        const float prevw = __shfl(v[k > 0 ? k - 1 : 0][3], 63);
        const float nextx = __shfl(v[k < AUNR - 1 ? k + 1 : AUNR - 1][0], 0);
        float xm = __shfl_up(v[k][3], 1);
        float xp = __shfl_down(v[k][0], 1);
        xm = (lane == 0)  ? ((k > 0)        ? prevw : xmE) : xm;
        xp = (lane == 63) ? ((k < AUNR - 1) ? nextx : xpE) : xp;

        unsigned int pb = 0;
        pb |= (v[k][0] > fmaxf(fmaxf(xm,      v[k][1]), THRM)) ? 1u : 0u;
        pb |= (v[k][1] > fmaxf(fmaxf(v[k][0], v[k][2]), THRM)) ? 2u : 0u;
        pb |= (v[k][2] > fmaxf(fmaxf(v[k][1], v[k][3]), THRM)) ? 4u : 0u;
        pb |= (v[k][3] > fmaxf(fmaxf(v[k][2], xp),      THRM)) ? 8u : 0u;

        maskb[(base + k * 256) >> 2] = (unsigned char)pb;   // coalesced bytes
        cnt += __popc(pb);
    }

    __shared__ unsigned int s[256];
    s[tid] = cnt;
    __syncthreads();
    for (int off = 128; off > 0; off >>= 1) {
        if (tid < off) s[tid] += s[tid + off];
        __syncthreads();
    }
    if (tid == 0) c1part[blockIdx.x] = s[0];
}

// Kernel B: one block per (aux n, batch b). Each wave owns a contiguous
// 12800-elem run; lane owns 8 contiguous elems per 512-elem step, so 6/8
// neighbor tests are register-local, 2 are intra-wave shuffles, and iter
// boundaries ride a carried register + the prefetched next buffer. Zero
// edge loads and zero barriers in the loop; 3 VMEM per 2KB, 2-deep pipeline.
__global__ __launch_bounds__(256) void aux_stats_kernel(
    const float* __restrict__ qa,
    const unsigned char* __restrict__ maskb,
    const unsigned int* __restrict__ c1part,
    float* __restrict__ out)
{
    const int n    = blockIdx.x >> 6;   // / NB
    const int b    = blockIdx.x & 63;   // % NB
    const int tid  = threadIdx.x;
    const int lane = tid & 63;
    const int w    = tid >> 6;
    const float* __restrict__ pn = qa + (size_t)n * NTOT;

    const int runbase  = b * PERB + w * RUNB;        // wave's contiguous run
    const int lanebase = runbase + lane * 8;

    // Run-edge neighbors: loaded ONCE (wave-uniform addresses, 1 line each).
    const float runL   = (runbase > 0)           ? pn[runbase - 1]    : INFINITY;
    const float runEnd = (runbase + RUNB < NTOT) ? pn[runbase + RUNB] : INFINITY;

    // Prologue: iteration 0 buffers.
    f32x4 c0 = __builtin_nontemporal_load(reinterpret_cast<const f32x4*>(pn + lanebase));
    f32x4 c1 = __builtin_nontemporal_load(reinterpret_cast<const f32x4*>(pn + lanebase + 4));
    unsigned int m = *reinterpret_cast<const unsigned short*>(maskb + (lanebase >> 2));

    float prevLast = runL;                 // left neighbor of the run so far
    unsigned int inter = 0, c2 = 0;

    for (int i = 0; i < NITB; ++i) {
        const bool last = (i == NITB - 1);
        f32x4 n0 = c0, n1 = c1; unsigned int nm = m;
        if (!last) {
            const int nb_ = lanebase + (i + 1) * STEPB;
            n0 = __builtin_nontemporal_load(reinterpret_cast<const f32x4*>(pn + nb_));
            n1 = __builtin_nontemporal_load(reinterpret_cast<const f32x4*>(pn + nb_ + 4));
            nm = *reinterpret_cast<const unsigned short*>(maskb + (nb_ >> 2));
        }
        const float nextFirst = last ? runEnd : __shfl(n0[0], 0);

        const float sUp = __shfl_up(c1[3], 1);
        const float sDn = __shfl_down(c0[0], 1);
        const float xmL = (lane == 0)  ? prevLast  : sUp;  // left  of elem 0
        const float xpR = (lane == 63) ? nextFirst : sDn;  // right of elem 7

        // peak(x) <=> x > max3(left, right, THRM); elems 0-3 -> bits 0-3,
        // elems 4-7 -> bits 8-11 (matches mask-ushort byte layout).
        unsigned int pb = 0;
        pb |= (c0[0] > fmaxf(fmaxf(xmL,   c0[1]), THRM)) ? 0x001u : 0u;
        pb |= (c0[1] > fmaxf(fmaxf(c0[0], c0[2]), THRM)) ? 0x002u : 0u;
        pb |= (c0[2] > fmaxf(fmaxf(c0[1], c0[3]), THRM)) ? 0x004u : 0u;
        pb |= (c0[3] > fmaxf(fmaxf(c0[2], c1[0]), THRM)) ? 0x008u : 0u;
        pb |= (c1[0] > fmaxf(fmaxf(c0[3], c1[1]), THRM)) ? 0x100u : 0u;
        pb |= (c1[1] > fmaxf(fmaxf(c1[0], c1[2]), THRM)) ? 0x200u : 0u;
        pb |= (c1[2] > fmaxf(fmaxf(c1[1], c1[3]), THRM)) ? 0x400u : 0u;
        pb |= (c1[3] > fmaxf(fmaxf(c1[2], xpR),   THRM)) ? 0x800u : 0u;

        c2    += __popc(pb);
        inter += __popc(pb & m);

        prevLast = __shfl(c1[3], 63);      // carry run-left for next iter
        c0 = n0; c1 = n1; m = nm;
    }

    __shared__ unsigned int si[256];
    __shared__ unsigned int sc[256];
    si[tid] = inter; sc[tid] = c2;
    __syncthreads();
    for (int off = 128; off > 0; off >>= 1) {
        if (tid < off) { si[tid] += si[tid + off]; sc[tid] += sc[tid + off]; }
        __syncthreads();
    }

    if (tid == 0) {
        unsigned int c1s = 0;
        #pragma unroll
        for (int s2 = 0; s2 < ASEG; ++s2) c1s += c1part[b * ASEG + s2];
        const float fi = (float)si[0];
        const float f1 = (float)c1s;
        const float f2 = (float)sc[0];
        const float un = f1 + f2 - fi;
        float jac, ratio;
        if (fi == 0.0f && un == 0.0f) {        // zero_union -> 1.0, 1.0
            jac = 1.0f; ratio = 1.0f;
        } else {
            jac   = fi / un;                              // un > 0 here
            ratio = (f1 > 0.0f) ? (fi / f1) : 0.0f;       // 0/0 -> nan_to_num -> 0
        }
        out[n * NB + b]             = jac;     // iou.reshape(-1)
        out[NAUX * NB + n * NB + b] = ratio;   // corr.reshape(-1)
    }
}

extern "C" void kernel_launch(void* const* d_in, const int* in_sizes, int n_in,
                              void* d_out, int out_size, void* d_ws, size_t ws_size,
                              hipStream_t stream) {
    const float* qs = (const float*)d_in[0];   // [64, 80, 640]
    const float* qa = (const float*)d_in[1];   // [32, 64, 80, 640]
    float* out = (float*)d_out;                // [4096] = iou ++ corr

    unsigned char* maskb = (unsigned char*)d_ws;                 // 819200 bytes
    unsigned int*  c1p   = (unsigned int*)(maskb + NGRP);        // 640 words

    strain_mask_kernel<<<NB * ASEG, 256, 0, stream>>>(qs, maskb, c1p);
    aux_stats_kernel<<<NAUX * NB, 256, 0, stream>>>(qa, maskb, c1p, out);
}